// Round 6
// baseline (2161.591 us; speedup 1.0000x reference)
//
#include <hip/hip_runtime.h>
#include <math.h>

#define NB   1024
#define NH   8
#define NDK  64
#define NDM  512
#define NP   49

// ---------------- fp32 SGEMM (Q/K projections: precision-pinned) ----------
#define BM 128
#define BN 128
#define BK 16

// C[M][N] = A[M][K] @ B[N][K]^T + bias[N]
__global__ __launch_bounds__(256) void sgemm_nt(
    const float* __restrict__ A,
    const float* __restrict__ B,
    const float* __restrict__ bias,
    float* __restrict__ C,
    int M, int N, int K)
{
    __shared__ float As[BK][BM + 4];
    __shared__ float Bs[BK][BN + 4];
    const int t  = threadIdx.x;
    const int tx = t & 15, ty = t >> 4;
    const int bm = blockIdx.y * BM, bn = blockIdx.x * BN;
    const float* Ab = A + (size_t)bm * K;
    const float* Bb = B + (size_t)bn * K;

    float acc[8][8];
#pragma unroll
    for (int i = 0; i < 8; ++i)
#pragma unroll
        for (int j = 0; j < 8; ++j) acc[i][j] = 0.f;

    for (int kt = 0; kt < K; kt += BK) {
#pragma unroll
        for (int u = 0; u < 2; ++u) {
            const int f   = t + u * 256;
            const int row = f >> 2;
            const int c0  = (f & 3) << 2;
            const float4 av = *(const float4*)(Ab + (size_t)row * K + kt + c0);
            const float4 bv = *(const float4*)(Bb + (size_t)row * K + kt + c0);
            As[c0 + 0][row] = av.x; As[c0 + 1][row] = av.y;
            As[c0 + 2][row] = av.z; As[c0 + 3][row] = av.w;
            Bs[c0 + 0][row] = bv.x; Bs[c0 + 1][row] = bv.y;
            Bs[c0 + 2][row] = bv.z; Bs[c0 + 3][row] = bv.w;
        }
        __syncthreads();
#pragma unroll
        for (int kk = 0; kk < BK; ++kk) {
            float a[8], b[8];
#pragma unroll
            for (int i = 0; i < 8; ++i) a[i] = As[kk][ty * 8 + i];
#pragma unroll
            for (int j = 0; j < 8; ++j) b[j] = Bs[kk][tx * 8 + j];
#pragma unroll
            for (int i = 0; i < 8; ++i)
#pragma unroll
                for (int j = 0; j < 8; ++j) acc[i][j] += a[i] * b[j];
        }
        __syncthreads();
    }

#pragma unroll
    for (int i = 0; i < 8; ++i) {
        const int r = bm + ty * 8 + i;
        float* Crow = C + (size_t)r * N + bn + tx * 8;
#pragma unroll
        for (int j4 = 0; j4 < 2; ++j4) {
            const int cb = bn + tx * 8 + j4 * 4;
            float4 o;
            o.x = acc[i][j4 * 4 + 0] + bias[cb + 0];
            o.y = acc[i][j4 * 4 + 1] + bias[cb + 1];
            o.z = acc[i][j4 * 4 + 2] + bias[cb + 2];
            o.w = acc[i][j4 * 4 + 3] + bias[cb + 3];
            *(float4*)(Crow + j4 * 4) = o;
        }
    }
}

// ---------------- bf16 MFMA GEMM (V / O projections: continuous path) -----
#define GBM 128
#define GBN 128
#define GBK 32
#define LDAB 40   // ushort stride = 80 B

typedef __attribute__((ext_vector_type(8))) short bf16x8;
typedef __attribute__((ext_vector_type(4))) float f32x4;

__device__ __forceinline__ unsigned short f2bf(float f) {  // RNE fp32->bf16
    unsigned u = __float_as_uint(f);
    return (unsigned short)((u + 0x7FFF + ((u >> 16) & 1)) >> 16);
}
__device__ __forceinline__ ushort4 f4tobf(float4 v) {
    ushort4 r;
    r.x = f2bf(v.x); r.y = f2bf(v.y); r.z = f2bf(v.z); r.w = f2bf(v.w);
    return r;
}

// C[M][N] = bf16(A[M][K]) @ bf16(B[N][K])^T + bias[N], fp32 accum/output
__global__ __launch_bounds__(256) void mgemm_nt(
    const float* __restrict__ A,
    const float* __restrict__ B,
    const float* __restrict__ bias,
    float* __restrict__ C,
    int M, int N, int K)
{
    __shared__ unsigned short As[GBM][LDAB];
    __shared__ unsigned short Bs[GBN][LDAB];

    const int t    = threadIdx.x;
    const int lane = t & 63;
    const int w    = t >> 6;
    const int wm   = (w >> 1) * 64;
    const int wn   = (w & 1) * 64;
    const int bm   = blockIdx.y * GBM, bn = blockIdx.x * GBN;

    const int tr = t >> 1;
    const int th = (t & 1) * 16;

    const int fr = lane & 15;
    const int fq = lane >> 4;

    f32x4 acc[4][4];
#pragma unroll
    for (int i = 0; i < 4; ++i)
#pragma unroll
        for (int j = 0; j < 4; ++j) acc[i][j] = (f32x4){0.f, 0.f, 0.f, 0.f};

    const float* Arow = A + (size_t)(bm + tr) * K + th;
    const float* Brow = B + (size_t)(bn + tr) * K + th;

    for (int kt = 0; kt < K; kt += GBK) {
        const float4* pa = (const float4*)(Arow + kt);
        const float4* pb = (const float4*)(Brow + kt);
        float4 a0 = pa[0], a1 = pa[1], a2 = pa[2], a3 = pa[3];
        float4 b0 = pb[0], b1 = pb[1], b2 = pb[2], b3 = pb[3];
        *(ushort4*)&As[tr][th +  0] = f4tobf(a0);
        *(ushort4*)&As[tr][th +  4] = f4tobf(a1);
        *(ushort4*)&As[tr][th +  8] = f4tobf(a2);
        *(ushort4*)&As[tr][th + 12] = f4tobf(a3);
        *(ushort4*)&Bs[tr][th +  0] = f4tobf(b0);
        *(ushort4*)&Bs[tr][th +  4] = f4tobf(b1);
        *(ushort4*)&Bs[tr][th +  8] = f4tobf(b2);
        *(ushort4*)&Bs[tr][th + 12] = f4tobf(b3);
        __syncthreads();

        bf16x8 af[4], bf[4];
#pragma unroll
        for (int fm = 0; fm < 4; ++fm)
            af[fm] = *(const bf16x8*)&As[wm + fm * 16 + fr][fq * 8];
#pragma unroll
        for (int fn = 0; fn < 4; ++fn)
            bf[fn] = *(const bf16x8*)&Bs[wn + fn * 16 + fr][fq * 8];
#pragma unroll
        for (int fm = 0; fm < 4; ++fm)
#pragma unroll
            for (int fn = 0; fn < 4; ++fn)
                acc[fm][fn] = __builtin_amdgcn_mfma_f32_16x16x32_bf16(
                    af[fm], bf[fn], acc[fm][fn], 0, 0, 0);
        __syncthreads();
    }

#pragma unroll
    for (int fn = 0; fn < 4; ++fn) {
        const int col = bn + wn + fn * 16 + fr;
        const float bs = bias[col];
#pragma unroll
        for (int fm = 0; fm < 4; ++fm) {
            const int r0 = bm + wm + fm * 16 + fq * 4;
#pragma unroll
            for (int r = 0; r < 4; ++r)
                C[(size_t)(r0 + r) * N + col] = acc[fm][fn][r] + bs;
        }
    }
}

// ---------------- A: scores -> transposed stripe in kbuf ------------------
// One block per (b,h). Reads q,k stripes; writes ssT[c][r] at kbuf stripe
// slot c*512 + r (k is dead after LDS staging; each block owns its stripe).
__global__ __launch_bounds__(192) void score_kernel(
    const float* __restrict__ qb,
    float* __restrict__ kb)
{
    const int bh = blockIdx.x;
    const int b = bh >> 3, h = bh & 7;

    __shared__ float qs[52][68];
    __shared__ float ks[52][68];

    const int t = threadIdx.x;
    const size_t base = ((size_t)b * NP) * NDM + (size_t)h * NDK;

    for (int i = t; i < 52 * 16; i += 192) {
        const int pos = i >> 4;
        const int c0  = (i & 15) << 2;
        float4 zq = make_float4(0.f, 0.f, 0.f, 0.f), zk = zq;
        if (pos < NP) {
            const size_t off = base + (size_t)pos * NDM + c0;
            zq = *(const float4*)(qb + off);
            zk = *(const float4*)(kb + off);
        }
        *(float4*)&qs[pos][c0] = zq;
        *(float4*)&ks[pos][c0] = zk;
    }
    __syncthreads();

    if (t < 169) {
        const int r0 = (t / 13) * 4;
        const int c0 = (t % 13) * 4;
        float acc[4][4];
#pragma unroll
        for (int i = 0; i < 4; ++i)
#pragma unroll
            for (int j = 0; j < 4; ++j) acc[i][j] = 0.f;
        for (int kk = 0; kk < NDK; kk += 4) {
            float4 a[4], bb[4];
#pragma unroll
            for (int i = 0; i < 4; ++i) a[i]  = *(const float4*)&qs[r0 + i][kk];
#pragma unroll
            for (int j = 0; j < 4; ++j) bb[j] = *(const float4*)&ks[c0 + j][kk];
#pragma unroll
            for (int i = 0; i < 4; ++i)
#pragma unroll
                for (int j = 0; j < 4; ++j)
                    acc[i][j] += a[i].x * bb[j].x + a[i].y * bb[j].y
                               + a[i].z * bb[j].z + a[i].w * bb[j].w;
        }
        // write ssT: slot (c, r) -> kbuf[base + c*512 + r]
#pragma unroll
        for (int j = 0; j < 4; ++j) {
            const int c = c0 + j;
            if (c < NP) {
                if (r0 <= 44) {
                    float4 o;
                    o.x = acc[0][j] * 0.125f; o.y = acc[1][j] * 0.125f;
                    o.z = acc[2][j] * 0.125f; o.w = acc[3][j] * 0.125f;
                    *(float4*)(kb + base + (size_t)c * NDM + r0) = o;
                } else {  // r0 == 48: only row 48 valid
                    kb[base + (size_t)c * NDM + 48] = acc[0][j] * 0.125f;
                }
            }
        }
    }
}

// ---------------- B: per-row topk/softmax/map/gate/softmax2 ---------------
// thread = global row (b,h,r). Reads ssT from kbuf stripe (slot c*512+r),
// writes p back IN PLACE (each thread owns exactly its 49 slots).
__global__ __launch_bounds__(256) void rowops_kernel(
    float* __restrict__ sb,
    const float* __restrict__ Wg,
    const float* __restrict__ Vg)
{
    __shared__ float gate[8][13];
    const int t = threadIdx.x;
    if (t < 104) {
        const int hh = t / 13, R = t - hh * 13;
        const float Wh = Wg[hh], Vh = Vg[hh];
        gate[hh][R] = (1.f + expf(Vh)) / (1.f + expf(Vh - Wh * (float)R));
    }
    __syncthreads();

    const int gid = blockIdx.x * 256 + t;       // grid exact: 8192*49 threads
    const int bh  = gid / 49;
    const int r   = gid - bh * 49;
    const int b   = bh >> 3, h = bh & 7;
    float* sp = sb + ((size_t)b * NP) * NDM + (size_t)h * NDK;

    float x[49];
#pragma unroll
    for (int c = 0; c < 49; ++c) x[c] = sp[(size_t)c * NDM + r];

    // top-11 by insertion (exact multiset)
    float top[11];
#pragma unroll
    for (int i = 0; i < 11; ++i) top[i] = -INFINITY;
#pragma unroll
    for (int c = 0; c < 49; ++c) {
        float xx = x[c];
#pragma unroll
        for (int i = 0; i < 11; ++i) {
            const float hi = fmaxf(top[i], xx);
            const float lo = fminf(top[i], xx);
            top[i] = hi; xx = lo;
        }
    }
    const float kth = top[10];   // 11th largest == 39th smallest
    const float m1  = top[0];

    float s = 0.f, smi = 0.f, smj = 0.f;
#pragma unroll
    for (int c = 0; c < 49; ++c) {
        if (x[c] >= kth) {                      // keep ties (att < kth -> -inf)
            const float e = expf(x[c] - m1);
            s   += e;
            smi += e * (float)(c / 7);
            smj += e * (float)(c % 7);
        }
    }
    const int pi = (int)rintf(smi / s);         // round-half-even == jnp.round
    const int pj = (int)rintf(smj / s);

    float m2 = 0.f;                             // all gated logits >= 0
#pragma unroll
    for (int c = 0; c < 49; ++c) {
        const int R = abs(pi - c / 7) + abs(pj - c % 7);
        const float l = fmaxf(x[c], 0.f) * gate[h][R];
        x[c] = l;
        m2 = fmaxf(m2, l);
    }
    float s2 = 0.f;
#pragma unroll
    for (int c = 0; c < 49; ++c) {
        const float e2 = expf(x[c] - m2);
        x[c] = e2;
        s2 += e2;
    }
    const float inv = 1.f / s2;
#pragma unroll
    for (int c = 0; c < 49; ++c) sp[(size_t)c * NDM + r] = x[c] * inv;
}

// ---------------- C: mid = p @ v ------------------------------------------
// One block per (b,h). Reads pT stripe (kbuf) + v stripe (vbuf); writes mid
// into qbuf stripe (q dead).
__global__ __launch_bounds__(256) void pv_kernel(
    const float* __restrict__ sb,
    const float* __restrict__ vb,
    float* __restrict__ mid)
{
    const int bh = blockIdx.x;
    const int b = bh >> 3, h = bh & 7;

    __shared__ float ps[49][52];   // pT: [c][r]
    __shared__ float vs[49][68];

    const int t = threadIdx.x;
    const size_t base = ((size_t)b * NP) * NDM + (size_t)h * NDK;

    for (int i = t; i < 49 * 13; i += 256) {    // pT rows: 13 float4 each
        const int c  = i / 13;
        const int rq = (i - c * 13) << 2;       // last one covers r=48..51 (dead slots ok)
        *(float4*)&ps[c][rq] = *(const float4*)(sb + base + (size_t)c * NDM + rq);
    }
    for (int i = t; i < 49 * 16; i += 256) {
        const int pos = i >> 4;
        const int c0  = (i & 15) << 2;
        *(float4*)&vs[pos][c0] = *(const float4*)(vb + base + (size_t)pos * NDM + c0);
    }
    __syncthreads();

    if (t < 208) {
        const int tr = t >> 4;           // rows 4tr..4tr+3
        const int d0 = (t & 15) << 2;    // output dims d0..d0+3
        float acc[4][4];
#pragma unroll
        for (int i = 0; i < 4; ++i)
#pragma unroll
            for (int j = 0; j < 4; ++j) acc[i][j] = 0.f;
        for (int c = 0; c < NP; ++c) {
            const float4 vv = *(const float4*)&vs[c][d0];
            const float4 pp = *(const float4*)&ps[c][4 * tr];
            const float p0 = pp.x, p1 = pp.y, p2 = pp.z, p3 = pp.w;
            acc[0][0] += p0 * vv.x; acc[0][1] += p0 * vv.y; acc[0][2] += p0 * vv.z; acc[0][3] += p0 * vv.w;
            acc[1][0] += p1 * vv.x; acc[1][1] += p1 * vv.y; acc[1][2] += p1 * vv.z; acc[1][3] += p1 * vv.w;
            acc[2][0] += p2 * vv.x; acc[2][1] += p2 * vv.y; acc[2][2] += p2 * vv.z; acc[2][3] += p2 * vv.w;
            acc[3][0] += p3 * vv.x; acc[3][1] += p3 * vv.y; acc[3][2] += p3 * vv.z; acc[3][3] += p3 * vv.w;
        }
#pragma unroll
        for (int i = 0; i < 4; ++i) {
            const int r = 4 * tr + i;
            if (r < NP) {
                float4 o;
                o.x = acc[i][0]; o.y = acc[i][1];
                o.z = acc[i][2]; o.w = acc[i][3];
                *(float4*)(mid + base + (size_t)r * NDM + d0) = o;
            }
        }
    }
}

extern "C" void kernel_launch(void* const* d_in, const int* in_sizes, int n_in,
                              void* d_out, int out_size, void* d_ws, size_t ws_size,
                              hipStream_t stream)
{
    (void)in_sizes; (void)n_in; (void)out_size; (void)ws_size;
    const float* queries = (const float*)d_in[0];
    const float* keys    = (const float*)d_in[1];
    const float* values  = (const float*)d_in[2];
    const float* Wq = (const float*)d_in[3];
    const float* bq = (const float*)d_in[4];
    const float* Wk = (const float*)d_in[5];
    const float* bk = (const float*)d_in[6];
    const float* Wv = (const float*)d_in[7];
    const float* bv = (const float*)d_in[8];
    const float* Wo = (const float*)d_in[9];
    const float* bo = (const float*)d_in[10];
    const float* Wg = (const float*)d_in[11];
    const float* Vg = (const float*)d_in[12];
    float* out = (float*)d_out;

    float* ws = (float*)d_ws;
    const size_t SZ = (size_t)NB * NP * NDM;   // 25,690,112 elements
    float* qbuf = ws;
    float* kbuf = ws + SZ;
    float* vbuf = ws + 2 * SZ;
    float* mid  = qbuf;                        // C writes mid into qbuf stripes

    const int M = NB * NP;                     // 50176
    dim3 blk(256);
    dim3 ggrid(NDM / BN, M / BM);              // (4, 392)

    hipLaunchKernelGGL(sgemm_nt, ggrid, blk, 0, stream, queries, Wq, bq, qbuf, M, NDM, NDM);
    hipLaunchKernelGGL(sgemm_nt, ggrid, blk, 0, stream, keys,    Wk, bk, kbuf, M, NDM, NDM);
    hipLaunchKernelGGL(mgemm_nt, ggrid, blk, 0, stream, values,  Wv, bv, vbuf, M, NDM, NDM);

    hipLaunchKernelGGL(score_kernel,  dim3(NB * NH), dim3(192), 0, stream, qbuf, kbuf);
    hipLaunchKernelGGL(rowops_kernel, dim3(NB * NH * NP / 256), blk, 0, stream, kbuf, Wg, Vg);
    hipLaunchKernelGGL(pv_kernel,     dim3(NB * NH), blk, 0, stream, kbuf, vbuf, mid);

    hipLaunchKernelGGL(mgemm_nt, ggrid, blk, 0, stream, mid, Wo, bo, out, M, NDM, NDM);
}

// Round 7
// 1424.652 us; speedup vs baseline: 1.5173x; 1.5173x over previous
//
#include <hip/hip_runtime.h>
#include <math.h>

#define NB   1024
#define NH   8
#define NDK  64
#define NDM  512
#define NP   49

// ---------------- fp32 SGEMM (Q/K projections: precision-pinned) ----------
#define BM 128
#define BN 128
#define BK 16

// C[M][N] = A[M][K] @ B[N][K]^T + bias[N]
__global__ __launch_bounds__(256) void sgemm_nt(
    const float* __restrict__ A,
    const float* __restrict__ B,
    const float* __restrict__ bias,
    float* __restrict__ C,
    int M, int N, int K)
{
    __shared__ float As[BK][BM + 4];
    __shared__ float Bs[BK][BN + 4];
    const int t  = threadIdx.x;
    const int tx = t & 15, ty = t >> 4;
    const int bm = blockIdx.y * BM, bn = blockIdx.x * BN;
    const float* Ab = A + (size_t)bm * K;
    const float* Bb = B + (size_t)bn * K;

    float acc[8][8];
#pragma unroll
    for (int i = 0; i < 8; ++i)
#pragma unroll
        for (int j = 0; j < 8; ++j) acc[i][j] = 0.f;

    for (int kt = 0; kt < K; kt += BK) {
#pragma unroll
        for (int u = 0; u < 2; ++u) {
            const int f   = t + u * 256;
            const int row = f >> 2;
            const int c0  = (f & 3) << 2;
            const float4 av = *(const float4*)(Ab + (size_t)row * K + kt + c0);
            const float4 bv = *(const float4*)(Bb + (size_t)row * K + kt + c0);
            As[c0 + 0][row] = av.x; As[c0 + 1][row] = av.y;
            As[c0 + 2][row] = av.z; As[c0 + 3][row] = av.w;
            Bs[c0 + 0][row] = bv.x; Bs[c0 + 1][row] = bv.y;
            Bs[c0 + 2][row] = bv.z; Bs[c0 + 3][row] = bv.w;
        }
        __syncthreads();
#pragma unroll
        for (int kk = 0; kk < BK; ++kk) {
            float a[8], b[8];
#pragma unroll
            for (int i = 0; i < 8; ++i) a[i] = As[kk][ty * 8 + i];
#pragma unroll
            for (int j = 0; j < 8; ++j) b[j] = Bs[kk][tx * 8 + j];
#pragma unroll
            for (int i = 0; i < 8; ++i)
#pragma unroll
                for (int j = 0; j < 8; ++j) acc[i][j] += a[i] * b[j];
        }
        __syncthreads();
    }

#pragma unroll
    for (int i = 0; i < 8; ++i) {
        const int r = bm + ty * 8 + i;
        float* Crow = C + (size_t)r * N + bn + tx * 8;
#pragma unroll
        for (int j4 = 0; j4 < 2; ++j4) {
            const int cb = bn + tx * 8 + j4 * 4;
            float4 o;
            o.x = acc[i][j4 * 4 + 0] + bias[cb + 0];
            o.y = acc[i][j4 * 4 + 1] + bias[cb + 1];
            o.z = acc[i][j4 * 4 + 2] + bias[cb + 2];
            o.w = acc[i][j4 * 4 + 3] + bias[cb + 3];
            *(float4*)(Crow + j4 * 4) = o;
        }
    }
}

// ---------------- bf16 MFMA GEMM (V / O projections: continuous path) -----
#define GBM 128
#define GBN 128
#define GBK 32
#define LDAB 40   // ushort stride = 80 B

typedef __attribute__((ext_vector_type(8))) short bf16x8;
typedef __attribute__((ext_vector_type(4))) float f32x4;

__device__ __forceinline__ unsigned short f2bf(float f) {  // RNE fp32->bf16
    unsigned u = __float_as_uint(f);
    return (unsigned short)((u + 0x7FFF + ((u >> 16) & 1)) >> 16);
}
__device__ __forceinline__ ushort4 f4tobf(float4 v) {
    ushort4 r;
    r.x = f2bf(v.x); r.y = f2bf(v.y); r.z = f2bf(v.z); r.w = f2bf(v.w);
    return r;
}

// C[M][N] = bf16(A[M][K]) @ bf16(B[N][K])^T + bias[N], fp32 accum/output
__global__ __launch_bounds__(256) void mgemm_nt(
    const float* __restrict__ A,
    const float* __restrict__ B,
    const float* __restrict__ bias,
    float* __restrict__ C,
    int M, int N, int K)
{
    __shared__ unsigned short As[GBM][LDAB];
    __shared__ unsigned short Bs[GBN][LDAB];

    const int t    = threadIdx.x;
    const int lane = t & 63;
    const int w    = t >> 6;
    const int wm   = (w >> 1) * 64;
    const int wn   = (w & 1) * 64;
    const int bm   = blockIdx.y * GBM, bn = blockIdx.x * GBN;

    const int tr = t >> 1;
    const int th = (t & 1) * 16;

    const int fr = lane & 15;
    const int fq = lane >> 4;

    f32x4 acc[4][4];
#pragma unroll
    for (int i = 0; i < 4; ++i)
#pragma unroll
        for (int j = 0; j < 4; ++j) acc[i][j] = (f32x4){0.f, 0.f, 0.f, 0.f};

    const float* Arow = A + (size_t)(bm + tr) * K + th;
    const float* Brow = B + (size_t)(bn + tr) * K + th;

    for (int kt = 0; kt < K; kt += GBK) {
        const float4* pa = (const float4*)(Arow + kt);
        const float4* pb = (const float4*)(Brow + kt);
        float4 a0 = pa[0], a1 = pa[1], a2 = pa[2], a3 = pa[3];
        float4 b0 = pb[0], b1 = pb[1], b2 = pb[2], b3 = pb[3];
        *(ushort4*)&As[tr][th +  0] = f4tobf(a0);
        *(ushort4*)&As[tr][th +  4] = f4tobf(a1);
        *(ushort4*)&As[tr][th +  8] = f4tobf(a2);
        *(ushort4*)&As[tr][th + 12] = f4tobf(a3);
        *(ushort4*)&Bs[tr][th +  0] = f4tobf(b0);
        *(ushort4*)&Bs[tr][th +  4] = f4tobf(b1);
        *(ushort4*)&Bs[tr][th +  8] = f4tobf(b2);
        *(ushort4*)&Bs[tr][th + 12] = f4tobf(b3);
        __syncthreads();

        bf16x8 af[4], bf[4];
#pragma unroll
        for (int fm = 0; fm < 4; ++fm)
            af[fm] = *(const bf16x8*)&As[wm + fm * 16 + fr][fq * 8];
#pragma unroll
        for (int fn = 0; fn < 4; ++fn)
            bf[fn] = *(const bf16x8*)&Bs[wn + fn * 16 + fr][fq * 8];
#pragma unroll
        for (int fm = 0; fm < 4; ++fm)
#pragma unroll
            for (int fn = 0; fn < 4; ++fn)
                acc[fm][fn] = __builtin_amdgcn_mfma_f32_16x16x32_bf16(
                    af[fm], bf[fn], acc[fm][fn], 0, 0, 0);
        __syncthreads();
    }

#pragma unroll
    for (int fn = 0; fn < 4; ++fn) {
        const int col = bn + wn + fn * 16 + fr;
        const float bs = bias[col];
#pragma unroll
        for (int fm = 0; fm < 4; ++fm) {
            const int r0 = bm + wm + fm * 16 + fq * 4;
#pragma unroll
            for (int r = 0; r < 4; ++r)
                C[(size_t)(r0 + r) * N + col] = acc[fm][fn][r] + bs;
        }
    }
}

// ---------------- A: scores -> transposed stripe in kbuf ------------------
// One block per (b,h). Writes ssT[c][r] at kbuf stripe slot c*512 + r for
// r in [0,64) — FULL 256B chunk coverage (rows 49..63 are zero pad) so every
// written cacheline is fully covered by same-wave float4 stores (no partial-
// line RMW / write amplification). Each block owns its stripe exclusively.
__global__ __launch_bounds__(256, 4) void score_kernel(
    const float* __restrict__ qb,
    float* __restrict__ kb)
{
    const int bh = blockIdx.x;
    const int b = bh >> 3, h = bh & 7;

    __shared__ float qs[52][68];
    __shared__ float ks[52][68];

    const int t = threadIdx.x;
    const size_t base = ((size_t)b * NP) * NDM + (size_t)h * NDK;

    for (int i = t; i < 52 * 16; i += 256) {
        const int pos = i >> 4;
        const int c0  = (i & 15) << 2;
        float4 zq = make_float4(0.f, 0.f, 0.f, 0.f), zk = zq;
        if (pos < NP) {
            const size_t off = base + (size_t)pos * NDM + c0;
            zq = *(const float4*)(qb + off);
            zk = *(const float4*)(kb + off);
        }
        *(float4*)&qs[pos][c0] = zq;
        *(float4*)&ks[pos][c0] = zk;
    }
    __syncthreads();

    // 16 row-groups x 13 col-groups = 208 threads; r0 = 0,4,...,60
    if (t < 208) {
        const int rg = t / 13;
        const int c0 = (t - rg * 13) * 4;
        const int r0 = rg * 4;

        float acc[4][4];
#pragma unroll
        for (int i = 0; i < 4; ++i)
#pragma unroll
            for (int j = 0; j < 4; ++j) acc[i][j] = 0.f;

        if (r0 < 52) {   // rows 49..51 read zeroed LDS pad -> acc stays 0
            for (int kk = 0; kk < NDK; kk += 4) {
                float4 a[4], bb[4];
#pragma unroll
                for (int i = 0; i < 4; ++i) a[i]  = *(const float4*)&qs[r0 + i][kk];
#pragma unroll
                for (int j = 0; j < 4; ++j) bb[j] = *(const float4*)&ks[c0 + j][kk];
#pragma unroll
                for (int i = 0; i < 4; ++i)
#pragma unroll
                    for (int j = 0; j < 4; ++j)
                        acc[i][j] += a[i].x * bb[j].x + a[i].y * bb[j].y
                                   + a[i].z * bb[j].z + a[i].w * bb[j].w;
            }
        }
        // write ssT: slot (c, r0..r0+3) -> kbuf[base + c*512 + r0]
#pragma unroll
        for (int j = 0; j < 4; ++j) {
            const int c = c0 + j;
            if (c < NP) {
                float4 o;
                o.x = acc[0][j] * 0.125f; o.y = acc[1][j] * 0.125f;
                o.z = acc[2][j] * 0.125f; o.w = acc[3][j] * 0.125f;
                *(float4*)(kb + base + (size_t)c * NDM + r0) = o;
            }
        }
    }
}

// ---------------- B: per-row topk/softmax/map/gate/softmax2 ---------------
// thread = global row (b,h,r). Reads ssT from kbuf stripe (slot c*512+r),
// writes p back IN PLACE (each thread owns exactly its 49 slots).
__global__ __launch_bounds__(256) void rowops_kernel(
    float* __restrict__ sb,
    const float* __restrict__ Wg,
    const float* __restrict__ Vg)
{
    __shared__ float gate[8][13];
    const int t = threadIdx.x;
    if (t < 104) {
        const int hh = t / 13, R = t - hh * 13;
        const float Wh = Wg[hh], Vh = Vg[hh];
        gate[hh][R] = (1.f + expf(Vh)) / (1.f + expf(Vh - Wh * (float)R));
    }
    __syncthreads();

    const int gid = blockIdx.x * 256 + t;       // grid exact: 8192*49 threads
    const int bh  = gid / 49;
    const int r   = gid - bh * 49;
    const int b   = bh >> 3, h = bh & 7;
    float* sp = sb + ((size_t)b * NP) * NDM + (size_t)h * NDK;

    float x[49];
#pragma unroll
    for (int c = 0; c < 49; ++c) x[c] = sp[(size_t)c * NDM + r];

    // top-11 by insertion (exact multiset)
    float top[11];
#pragma unroll
    for (int i = 0; i < 11; ++i) top[i] = -INFINITY;
#pragma unroll
    for (int c = 0; c < 49; ++c) {
        float xx = x[c];
#pragma unroll
        for (int i = 0; i < 11; ++i) {
            const float hi = fmaxf(top[i], xx);
            const float lo = fminf(top[i], xx);
            top[i] = hi; xx = lo;
        }
    }
    const float kth = top[10];   // 11th largest == 39th smallest
    const float m1  = top[0];

    float s = 0.f, smi = 0.f, smj = 0.f;
#pragma unroll
    for (int c = 0; c < 49; ++c) {
        if (x[c] >= kth) {                      // keep ties (att < kth -> -inf)
            const float e = expf(x[c] - m1);
            s   += e;
            smi += e * (float)(c / 7);
            smj += e * (float)(c % 7);
        }
    }
    const int pi = (int)rintf(smi / s);         // round-half-even == jnp.round
    const int pj = (int)rintf(smj / s);

    float m2 = 0.f;                             // all gated logits >= 0
#pragma unroll
    for (int c = 0; c < 49; ++c) {
        const int R = abs(pi - c / 7) + abs(pj - c % 7);
        const float l = fmaxf(x[c], 0.f) * gate[h][R];
        x[c] = l;
        m2 = fmaxf(m2, l);
    }
    float s2 = 0.f;
#pragma unroll
    for (int c = 0; c < 49; ++c) {
        const float e2 = expf(x[c] - m2);
        x[c] = e2;
        s2 += e2;
    }
    const float inv = 1.f / s2;
#pragma unroll
    for (int c = 0; c < 49; ++c) sp[(size_t)c * NDM + r] = x[c] * inv;
}

// ---------------- C: mid = p @ v ------------------------------------------
// One block per (b,h). Reads pT stripe (kbuf) + v stripe (vbuf); writes mid
// into qbuf stripe (q dead).
__global__ __launch_bounds__(256) void pv_kernel(
    const float* __restrict__ sb,
    const float* __restrict__ vb,
    float* __restrict__ mid)
{
    const int bh = blockIdx.x;
    const int b = bh >> 3, h = bh & 7;

    __shared__ float ps[49][52];   // pT: [c][r]
    __shared__ float vs[49][68];

    const int t = threadIdx.x;
    const size_t base = ((size_t)b * NP) * NDM + (size_t)h * NDK;

    for (int i = t; i < 49 * 13; i += 256) {    // pT rows: 13 float4 each
        const int c  = i / 13;
        const int rq = (i - c * 13) << 2;       // r=48..51 are zero pad, fine
        *(float4*)&ps[c][rq] = *(const float4*)(sb + base + (size_t)c * NDM + rq);
    }
    for (int i = t; i < 49 * 16; i += 256) {
        const int pos = i >> 4;
        const int c0  = (i & 15) << 2;
        *(float4*)&vs[pos][c0] = *(const float4*)(vb + base + (size_t)pos * NDM + c0);
    }
    __syncthreads();

    if (t < 208) {
        const int tr = t >> 4;           // rows 4tr..4tr+3
        const int d0 = (t & 15) << 2;    // output dims d0..d0+3
        float acc[4][4];
#pragma unroll
        for (int i = 0; i < 4; ++i)
#pragma unroll
            for (int j = 0; j < 4; ++j) acc[i][j] = 0.f;
        for (int c = 0; c < NP; ++c) {
            const float4 vv = *(const float4*)&vs[c][d0];
            const float4 pp = *(const float4*)&ps[c][4 * tr];
            const float p0 = pp.x, p1 = pp.y, p2 = pp.z, p3 = pp.w;
            acc[0][0] += p0 * vv.x; acc[0][1] += p0 * vv.y; acc[0][2] += p0 * vv.z; acc[0][3] += p0 * vv.w;
            acc[1][0] += p1 * vv.x; acc[1][1] += p1 * vv.y; acc[1][2] += p1 * vv.z; acc[1][3] += p1 * vv.w;
            acc[2][0] += p2 * vv.x; acc[2][1] += p2 * vv.y; acc[2][2] += p2 * vv.z; acc[2][3] += p2 * vv.w;
            acc[3][0] += p3 * vv.x; acc[3][1] += p3 * vv.y; acc[3][2] += p3 * vv.z; acc[3][3] += p3 * vv.w;
        }
#pragma unroll
        for (int i = 0; i < 4; ++i) {
            const int r = 4 * tr + i;
            if (r < NP) {
                float4 o;
                o.x = acc[i][0]; o.y = acc[i][1];
                o.z = acc[i][2]; o.w = acc[i][3];
                *(float4*)(mid + base + (size_t)r * NDM + d0) = o;
            }
        }
    }
}

extern "C" void kernel_launch(void* const* d_in, const int* in_sizes, int n_in,
                              void* d_out, int out_size, void* d_ws, size_t ws_size,
                              hipStream_t stream)
{
    (void)in_sizes; (void)n_in; (void)out_size; (void)ws_size;
    const float* queries = (const float*)d_in[0];
    const float* keys    = (const float*)d_in[1];
    const float* values  = (const float*)d_in[2];
    const float* Wq = (const float*)d_in[3];
    const float* bq = (const float*)d_in[4];
    const float* Wk = (const float*)d_in[5];
    const float* bk = (const float*)d_in[6];
    const float* Wv = (const float*)d_in[7];
    const float* bv = (const float*)d_in[8];
    const float* Wo = (const float*)d_in[9];
    const float* bo = (const float*)d_in[10];
    const float* Wg = (const float*)d_in[11];
    const float* Vg = (const float*)d_in[12];
    float* out = (float*)d_out;

    float* ws = (float*)d_ws;
    const size_t SZ = (size_t)NB * NP * NDM;   // 25,690,112 elements
    float* qbuf = ws;
    float* kbuf = ws + SZ;
    float* vbuf = ws + 2 * SZ;
    float* mid  = qbuf;                        // C writes mid into qbuf stripes

    const int M = NB * NP;                     // 50176
    dim3 blk(256);
    dim3 ggrid(NDM / BN, M / BM);              // (4, 392)

    hipLaunchKernelGGL(sgemm_nt, ggrid, blk, 0, stream, queries, Wq, bq, qbuf, M, NDM, NDM);
    hipLaunchKernelGGL(sgemm_nt, ggrid, blk, 0, stream, keys,    Wk, bk, kbuf, M, NDM, NDM);
    hipLaunchKernelGGL(mgemm_nt, ggrid, blk, 0, stream, values,  Wv, bv, vbuf, M, NDM, NDM);

    hipLaunchKernelGGL(score_kernel,  dim3(NB * NH), blk, 0, stream, qbuf, kbuf);
    hipLaunchKernelGGL(rowops_kernel, dim3(NB * NH * NP / 256), blk, 0, stream, kbuf, Wg, Vg);
    hipLaunchKernelGGL(pv_kernel,     dim3(NB * NH), blk, 0, stream, kbuf, vbuf, mid);

    hipLaunchKernelGGL(mgemm_nt, ggrid, blk, 0, stream, mid, Wo, bo, out, M, NDM, NDM);
}

// Round 8
// 1404.547 us; speedup vs baseline: 1.5390x; 1.0143x over previous
//
#include <hip/hip_runtime.h>
#include <math.h>

#define NB   1024
#define NH   8
#define NDK  64
#define NDM  512
#define NP   49

// ---------------- fp32 SGEMM (Q/K projections: precision-pinned) ----------
#define BM 128
#define BN 128
#define BK 32

// C[M][N] = A[M][K] @ B[N][K]^T + bias[N]
// Thread tx owns cols {tx*4..+3} and {64+tx*4..+3}: B-reads are contiguous
// 256B per 16 lanes (2-way bank aliasing only); A-reads are broadcasts.
__global__ __launch_bounds__(256) void sgemm_nt(
    const float* __restrict__ A,
    const float* __restrict__ B,
    const float* __restrict__ bias,
    float* __restrict__ C,
    int M, int N, int K)
{
    __shared__ float As[BK][BM + 4];
    __shared__ float Bs[BK][BN + 4];
    const int t  = threadIdx.x;
    const int tx = t & 15, ty = t >> 4;
    const int bm = blockIdx.y * BM, bn = blockIdx.x * BN;
    const float* Ab = A + (size_t)bm * K;
    const float* Bb = B + (size_t)bn * K;

    float acc[8][8];
#pragma unroll
    for (int i = 0; i < 8; ++i)
#pragma unroll
        for (int j = 0; j < 8; ++j) acc[i][j] = 0.f;

    for (int kt = 0; kt < K; kt += BK) {
#pragma unroll
        for (int u = 0; u < 4; ++u) {
            const int f   = t + (u << 8);
            const int row = f >> 3;
            const int c0  = (f & 7) << 2;
            const float4 av = *(const float4*)(Ab + (size_t)row * K + kt + c0);
            const float4 bv = *(const float4*)(Bb + (size_t)row * K + kt + c0);
            As[c0 + 0][row] = av.x; As[c0 + 1][row] = av.y;
            As[c0 + 2][row] = av.z; As[c0 + 3][row] = av.w;
            Bs[c0 + 0][row] = bv.x; Bs[c0 + 1][row] = bv.y;
            Bs[c0 + 2][row] = bv.z; Bs[c0 + 3][row] = bv.w;
        }
        __syncthreads();
#pragma unroll
        for (int kk = 0; kk < BK; ++kk) {
            const float4 a0 = *(const float4*)&As[kk][ty * 8];
            const float4 a1 = *(const float4*)&As[kk][ty * 8 + 4];
            const float4 b0 = *(const float4*)&Bs[kk][tx * 4];
            const float4 b1 = *(const float4*)&Bs[kk][64 + tx * 4];
            const float a[8] = {a0.x, a0.y, a0.z, a0.w, a1.x, a1.y, a1.z, a1.w};
            const float b[8] = {b0.x, b0.y, b0.z, b0.w, b1.x, b1.y, b1.z, b1.w};
#pragma unroll
            for (int i = 0; i < 8; ++i)
#pragma unroll
                for (int j = 0; j < 8; ++j) acc[i][j] += a[i] * b[j];
        }
        __syncthreads();
    }

#pragma unroll
    for (int i = 0; i < 8; ++i) {
        const int r = bm + ty * 8 + i;
        float* Crow = C + (size_t)r * N;
        {
            const int cb = bn + tx * 4;
            float4 o;
            o.x = acc[i][0] + bias[cb + 0];
            o.y = acc[i][1] + bias[cb + 1];
            o.z = acc[i][2] + bias[cb + 2];
            o.w = acc[i][3] + bias[cb + 3];
            *(float4*)(Crow + cb) = o;
        }
        {
            const int cb = bn + 64 + tx * 4;
            float4 o;
            o.x = acc[i][4] + bias[cb + 0];
            o.y = acc[i][5] + bias[cb + 1];
            o.z = acc[i][6] + bias[cb + 2];
            o.w = acc[i][7] + bias[cb + 3];
            *(float4*)(Crow + cb) = o;
        }
    }
}

// ---------------- bf16 MFMA GEMM (V / O projections: continuous path) -----
#define GBM 128
#define GBN 128
#define GBK 32
#define LDAB 40   // ushort stride = 80 B

typedef __attribute__((ext_vector_type(8))) short bf16x8;
typedef __attribute__((ext_vector_type(4))) float f32x4;

__device__ __forceinline__ unsigned short f2bf(float f) {  // RNE fp32->bf16
    unsigned u = __float_as_uint(f);
    return (unsigned short)((u + 0x7FFF + ((u >> 16) & 1)) >> 16);
}
__device__ __forceinline__ ushort4 f4tobf(float4 v) {
    ushort4 r;
    r.x = f2bf(v.x); r.y = f2bf(v.y); r.z = f2bf(v.z); r.w = f2bf(v.w);
    return r;
}

// C[M][N] = bf16(A[M][K]) @ bf16(B[N][K])^T + bias[N], fp32 accum/output
__global__ __launch_bounds__(256) void mgemm_nt(
    const float* __restrict__ A,
    const float* __restrict__ B,
    const float* __restrict__ bias,
    float* __restrict__ C,
    int M, int N, int K)
{
    __shared__ unsigned short As[GBM][LDAB];
    __shared__ unsigned short Bs[GBN][LDAB];

    const int t    = threadIdx.x;
    const int lane = t & 63;
    const int w    = t >> 6;
    const int wm   = (w >> 1) * 64;
    const int wn   = (w & 1) * 64;
    const int bm   = blockIdx.y * GBM, bn = blockIdx.x * GBN;

    const int tr = t >> 1;
    const int th = (t & 1) * 16;

    const int fr = lane & 15;
    const int fq = lane >> 4;

    f32x4 acc[4][4];
#pragma unroll
    for (int i = 0; i < 4; ++i)
#pragma unroll
        for (int j = 0; j < 4; ++j) acc[i][j] = (f32x4){0.f, 0.f, 0.f, 0.f};

    const float* Arow = A + (size_t)(bm + tr) * K + th;
    const float* Brow = B + (size_t)(bn + tr) * K + th;

    for (int kt = 0; kt < K; kt += GBK) {
        const float4* pa = (const float4*)(Arow + kt);
        const float4* pb = (const float4*)(Brow + kt);
        float4 a0 = pa[0], a1 = pa[1], a2 = pa[2], a3 = pa[3];
        float4 b0 = pb[0], b1 = pb[1], b2 = pb[2], b3 = pb[3];
        *(ushort4*)&As[tr][th +  0] = f4tobf(a0);
        *(ushort4*)&As[tr][th +  4] = f4tobf(a1);
        *(ushort4*)&As[tr][th +  8] = f4tobf(a2);
        *(ushort4*)&As[tr][th + 12] = f4tobf(a3);
        *(ushort4*)&Bs[tr][th +  0] = f4tobf(b0);
        *(ushort4*)&Bs[tr][th +  4] = f4tobf(b1);
        *(ushort4*)&Bs[tr][th +  8] = f4tobf(b2);
        *(ushort4*)&Bs[tr][th + 12] = f4tobf(b3);
        __syncthreads();

        bf16x8 af[4], bf[4];
#pragma unroll
        for (int fm = 0; fm < 4; ++fm)
            af[fm] = *(const bf16x8*)&As[wm + fm * 16 + fr][fq * 8];
#pragma unroll
        for (int fn = 0; fn < 4; ++fn)
            bf[fn] = *(const bf16x8*)&Bs[wn + fn * 16 + fr][fq * 8];
#pragma unroll
        for (int fm = 0; fm < 4; ++fm)
#pragma unroll
            for (int fn = 0; fn < 4; ++fn)
                acc[fm][fn] = __builtin_amdgcn_mfma_f32_16x16x32_bf16(
                    af[fm], bf[fn], acc[fm][fn], 0, 0, 0);
        __syncthreads();
    }

#pragma unroll
    for (int fn = 0; fn < 4; ++fn) {
        const int col = bn + wn + fn * 16 + fr;
        const float bs = bias[col];
#pragma unroll
        for (int fm = 0; fm < 4; ++fm) {
            const int r0 = bm + wm + fm * 16 + fq * 4;
#pragma unroll
            for (int r = 0; r < 4; ++r)
                C[(size_t)(r0 + r) * N + col] = acc[fm][fn][r] + bs;
        }
    }
}

// ---------------- A: scores -> transposed stripe in kbuf ------------------
// One block per (b,h). Writes ssT[c][r] at kbuf stripe slot c*512 + r for
// r in [0,64) — FULL 256B chunk coverage (rows 49..63 are zero pad) so every
// written cacheline is fully covered by same-wave float4 stores (no partial-
// line RMW / write amplification). Each block owns its stripe exclusively.
__global__ __launch_bounds__(256, 4) void score_kernel(
    const float* __restrict__ qb,
    float* __restrict__ kb)
{
    const int bh = blockIdx.x;
    const int b = bh >> 3, h = bh & 7;

    __shared__ float qs[52][68];
    __shared__ float ks[52][68];

    const int t = threadIdx.x;
    const size_t base = ((size_t)b * NP) * NDM + (size_t)h * NDK;

    for (int i = t; i < 52 * 16; i += 256) {
        const int pos = i >> 4;
        const int c0  = (i & 15) << 2;
        float4 zq = make_float4(0.f, 0.f, 0.f, 0.f), zk = zq;
        if (pos < NP) {
            const size_t off = base + (size_t)pos * NDM + c0;
            zq = *(const float4*)(qb + off);
            zk = *(const float4*)(kb + off);
        }
        *(float4*)&qs[pos][c0] = zq;
        *(float4*)&ks[pos][c0] = zk;
    }
    __syncthreads();

    // 16 row-groups x 13 col-groups = 208 threads; r0 = 0,4,...,60
    if (t < 208) {
        const int rg = t / 13;
        const int c0 = (t - rg * 13) * 4;
        const int r0 = rg * 4;

        float acc[4][4];
#pragma unroll
        for (int i = 0; i < 4; ++i)
#pragma unroll
            for (int j = 0; j < 4; ++j) acc[i][j] = 0.f;

        if (r0 < 52) {   // rows 49..51 read zeroed LDS pad -> acc stays 0
            for (int kk = 0; kk < NDK; kk += 4) {
                float4 a[4], bb[4];
#pragma unroll
                for (int i = 0; i < 4; ++i) a[i]  = *(const float4*)&qs[r0 + i][kk];
#pragma unroll
                for (int j = 0; j < 4; ++j) bb[j] = *(const float4*)&ks[c0 + j][kk];
#pragma unroll
                for (int i = 0; i < 4; ++i)
#pragma unroll
                    for (int j = 0; j < 4; ++j)
                        acc[i][j] += a[i].x * bb[j].x + a[i].y * bb[j].y
                                   + a[i].z * bb[j].z + a[i].w * bb[j].w;
            }
        }
        // write ssT: slot (c, r0..r0+3) -> kbuf[base + c*512 + r0]
#pragma unroll
        for (int j = 0; j < 4; ++j) {
            const int c = c0 + j;
            if (c < NP) {
                float4 o;
                o.x = acc[0][j] * 0.125f; o.y = acc[1][j] * 0.125f;
                o.z = acc[2][j] * 0.125f; o.w = acc[3][j] * 0.125f;
                *(float4*)(kb + base + (size_t)c * NDM + r0) = o;
            }
        }
    }
}

// ---------------- B: per-row topk/softmax/map/gate/softmax2 ---------------
// thread = global row (b,h,r). Reads ssT from kbuf stripe (slot c*512+r),
// writes p back IN PLACE (each thread owns exactly its 49 slots).
__global__ __launch_bounds__(256) void rowops_kernel(
    float* __restrict__ sb,
    const float* __restrict__ Wg,
    const float* __restrict__ Vg)
{
    __shared__ float gate[8][13];
    const int t = threadIdx.x;
    if (t < 104) {
        const int hh = t / 13, R = t - hh * 13;
        const float Wh = Wg[hh], Vh = Vg[hh];
        gate[hh][R] = (1.f + expf(Vh)) / (1.f + expf(Vh - Wh * (float)R));
    }
    __syncthreads();

    const int gid = blockIdx.x * 256 + t;       // grid exact: 8192*49 threads
    const int bh  = gid / 49;
    const int r   = gid - bh * 49;
    const int b   = bh >> 3, h = bh & 7;
    float* sp = sb + ((size_t)b * NP) * NDM + (size_t)h * NDK;

    float x[49];
#pragma unroll
    for (int c = 0; c < 49; ++c) x[c] = sp[(size_t)c * NDM + r];

    // top-11 by insertion (exact multiset)
    float top[11];
#pragma unroll
    for (int i = 0; i < 11; ++i) top[i] = -INFINITY;
#pragma unroll
    for (int c = 0; c < 49; ++c) {
        float xx = x[c];
#pragma unroll
        for (int i = 0; i < 11; ++i) {
            const float hi = fmaxf(top[i], xx);
            const float lo = fminf(top[i], xx);
            top[i] = hi; xx = lo;
        }
    }
    const float kth = top[10];   // 11th largest == 39th smallest
    const float m1  = top[0];

    float s = 0.f, smi = 0.f, smj = 0.f;
#pragma unroll
    for (int c = 0; c < 49; ++c) {
        if (x[c] >= kth) {                      // keep ties (att < kth -> -inf)
            const float e = expf(x[c] - m1);
            s   += e;
            smi += e * (float)(c / 7);
            smj += e * (float)(c % 7);
        }
    }
    const int pi = (int)rintf(smi / s);         // round-half-even == jnp.round
    const int pj = (int)rintf(smj / s);

    float m2 = 0.f;                             // all gated logits >= 0
#pragma unroll
    for (int c = 0; c < 49; ++c) {
        const int R = abs(pi - c / 7) + abs(pj - c % 7);
        const float l = fmaxf(x[c], 0.f) * gate[h][R];
        x[c] = l;
        m2 = fmaxf(m2, l);
    }
    float s2 = 0.f;
#pragma unroll
    for (int c = 0; c < 49; ++c) {
        const float e2 = expf(x[c] - m2);
        x[c] = e2;
        s2 += e2;
    }
    const float inv = 1.f / s2;
#pragma unroll
    for (int c = 0; c < 49; ++c) sp[(size_t)c * NDM + r] = x[c] * inv;
}

// ---------------- C: mid = p @ v ------------------------------------------
// One block per (b,h). Reads pT stripe (kbuf) + v stripe (vbuf); writes mid
// into qbuf stripe (q dead).
__global__ __launch_bounds__(256) void pv_kernel(
    const float* __restrict__ sb,
    const float* __restrict__ vb,
    float* __restrict__ mid)
{
    const int bh = blockIdx.x;
    const int b = bh >> 3, h = bh & 7;

    __shared__ float ps[49][52];   // pT: [c][r]
    __shared__ float vs[49][68];

    const int t = threadIdx.x;
    const size_t base = ((size_t)b * NP) * NDM + (size_t)h * NDK;

    for (int i = t; i < 49 * 13; i += 256) {    // pT rows: 13 float4 each
        const int c  = i / 13;
        const int rq = (i - c * 13) << 2;       // r=48..51 are zero pad, fine
        *(float4*)&ps[c][rq] = *(const float4*)(sb + base + (size_t)c * NDM + rq);
    }
    for (int i = t; i < 49 * 16; i += 256) {
        const int pos = i >> 4;
        const int c0  = (i & 15) << 2;
        *(float4*)&vs[pos][c0] = *(const float4*)(vb + base + (size_t)pos * NDM + c0);
    }
    __syncthreads();

    if (t < 208) {
        const int tr = t >> 4;           // rows 4tr..4tr+3
        const int d0 = (t & 15) << 2;    // output dims d0..d0+3
        float acc[4][4];
#pragma unroll
        for (int i = 0; i < 4; ++i)
#pragma unroll
            for (int j = 0; j < 4; ++j) acc[i][j] = 0.f;
        for (int c = 0; c < NP; ++c) {
            const float4 vv = *(const float4*)&vs[c][d0];
            const float4 pp = *(const float4*)&ps[c][4 * tr];
            const float p0 = pp.x, p1 = pp.y, p2 = pp.z, p3 = pp.w;
            acc[0][0] += p0 * vv.x; acc[0][1] += p0 * vv.y; acc[0][2] += p0 * vv.z; acc[0][3] += p0 * vv.w;
            acc[1][0] += p1 * vv.x; acc[1][1] += p1 * vv.y; acc[1][2] += p1 * vv.z; acc[1][3] += p1 * vv.w;
            acc[2][0] += p2 * vv.x; acc[2][1] += p2 * vv.y; acc[2][2] += p2 * vv.z; acc[2][3] += p2 * vv.w;
            acc[3][0] += p3 * vv.x; acc[3][1] += p3 * vv.y; acc[3][2] += p3 * vv.z; acc[3][3] += p3 * vv.w;
        }
#pragma unroll
        for (int i = 0; i < 4; ++i) {
            const int r = 4 * tr + i;
            if (r < NP) {
                float4 o;
                o.x = acc[i][0]; o.y = acc[i][1];
                o.z = acc[i][2]; o.w = acc[i][3];
                *(float4*)(mid + base + (size_t)r * NDM + d0) = o;
            }
        }
    }
}

extern "C" void kernel_launch(void* const* d_in, const int* in_sizes, int n_in,
                              void* d_out, int out_size, void* d_ws, size_t ws_size,
                              hipStream_t stream)
{
    (void)in_sizes; (void)n_in; (void)out_size; (void)ws_size;
    const float* queries = (const float*)d_in[0];
    const float* keys    = (const float*)d_in[1];
    const float* values  = (const float*)d_in[2];
    const float* Wq = (const float*)d_in[3];
    const float* bq = (const float*)d_in[4];
    const float* Wk = (const float*)d_in[5];
    const float* bk = (const float*)d_in[6];
    const float* Wv = (const float*)d_in[7];
    const float* bv = (const float*)d_in[8];
    const float* Wo = (const float*)d_in[9];
    const float* bo = (const float*)d_in[10];
    const float* Wg = (const float*)d_in[11];
    const float* Vg = (const float*)d_in[12];
    float* out = (float*)d_out;

    float* ws = (float*)d_ws;
    const size_t SZ = (size_t)NB * NP * NDM;   // 25,690,112 elements
    float* qbuf = ws;
    float* kbuf = ws + SZ;
    float* vbuf = ws + 2 * SZ;
    float* mid  = qbuf;                        // C writes mid into qbuf stripes

    const int M = NB * NP;                     // 50176
    dim3 blk(256);
    dim3 ggrid(NDM / BN, M / BM);              // (4, 392)

    hipLaunchKernelGGL(sgemm_nt, ggrid, blk, 0, stream, queries, Wq, bq, qbuf, M, NDM, NDM);
    hipLaunchKernelGGL(sgemm_nt, ggrid, blk, 0, stream, keys,    Wk, bk, kbuf, M, NDM, NDM);
    hipLaunchKernelGGL(mgemm_nt, ggrid, blk, 0, stream, values,  Wv, bv, vbuf, M, NDM, NDM);

    hipLaunchKernelGGL(score_kernel,  dim3(NB * NH), blk, 0, stream, qbuf, kbuf);
    hipLaunchKernelGGL(rowops_kernel, dim3(NB * NH * NP / 256), blk, 0, stream, kbuf, Wg, Vg);
    hipLaunchKernelGGL(pv_kernel,     dim3(NB * NH), blk, 0, stream, kbuf, vbuf, mid);

    hipLaunchKernelGGL(mgemm_nt, ggrid, blk, 0, stream, mid, Wo, bo, out, M, NDM, NDM);
}